// Round 1
// baseline (621.185 us; speedup 1.0000x reference)
//
#include <hip/hip_runtime.h>
#include <cstddef>

// ---------------- problem constants ----------------
#define NB 16
#define NC 256
#define NH 32
#define NW 32
#define NK 81

// LDS float offsets (total 37,248 floats = 148,992 B, 1 block/CU)
// Strides chosen so (addr>>2)&7 spreads across all 8 bank-groups:
//   row stride 36 floats -> 9*row = row (mod 8)  [conflict-free vs old 32]
#define L_FLT    0        // [256][36]  flt row
#define L_FG     9216     // [256][36]  filter-grad row
#define L_MRES   18432    // [81][36]   mapped residuals (C reuses as sg^2 scratch)
#define L_SMASK  21348    // [81][36]
#define L_FS     24264    // A/C: [32ch][9dy][44]=12672; red: 4x2916; B: [256][44]=11264; part: [128][36]=4608
#define L_CL     36936    // local consts [245]
#define L_ANUM   37184    // [32]
#define L_ALPHA  37216    // [32]
#define L_TOTAL  37248

__device__ __forceinline__ float4 ld4(const float* p) { return *reinterpret_cast<const float4*>(p); }
__device__ __forceinline__ void st4(float* p, float4 v) { *reinterpret_cast<float4*>(p) = v; }

__device__ __forceinline__ void map_by(int bi, int& b, int& y) {
    int xcd = bi & 7, slot = bi >> 3;
    b = xcd * 2 + (slot >> 5);
    y = slot & 31;
}

// Correlation pass: scores(k,x) = sum_c A[c,x]*featpad[c,y+dy,x+dx-4]
// Results left in 4 red buffers at S[L_FS + p*2916] (stride-36 rows), consumer sums the 4.
__device__ __forceinline__ void corr_pass(float* S, const float* __restrict__ feat,
                                          int a_off, int b, int y, int tid,
                                          int lg, int oct, int dyA,
                                          int qs, int c0s, int dys, bool vst, int rys) {
    float* fs = S + L_FS;
    // prefetch chunk-0 global loads before the zero phase (hide latency)
    const float* gbase = feat + (((size_t)b * NC) * NH + rys) * NW + qs * 4;
    float4 R[4];
    if (vst) {
#pragma unroll
        for (int k2 = 0; k2 < 4; k2++)
            R[k2] = ld4(gbase + (size_t)(c0s + 8 * k2) * (NH * NW));
    }
    const float4 z4 = make_float4(0.f, 0.f, 0.f, 0.f);
    // zero only halo quads (floats 0..3 and 36..39 of each of the 288 [44] rows)
    {
        int row = tid >> 1;
        st4(fs + row * 44 + ((tid & 1) ? 36 : 0), z4);
    }
    // zero full rows of out-of-range dy (only near y edges)
    if (y < 4 || y > 27) {
        for (int dyv = 0; dyv < 9; ++dyv) {
            int ryv = y + dyv - 4;
            if (ryv < 0 || ryv >= 32) {
                for (int i = tid; i < 320; i += 576) {
                    int c = i / 10, q = i - c * 10;
                    st4(fs + c * 396 + dyv * 44 + q * 4, z4);
                }
            }
        }
    }
    __syncthreads();

    float acc[9][8];
#pragma unroll
    for (int dx = 0; dx < 9; dx++)
#pragma unroll
        for (int i = 0; i < 8; i++) acc[dx][i] = 0.f;

#pragma unroll 1
    for (int chunk = 0; chunk < 8; chunk++) {
        if (vst) {
#pragma unroll
            for (int k2 = 0; k2 < 4; k2++)
                st4(fs + (c0s + 8 * k2) * 396 + dys * 44 + 4 + qs * 4, R[k2]);
        }
        __syncthreads();
        if (chunk < 7 && vst) {
#pragma unroll
            for (int k2 = 0; k2 < 4; k2++)
                R[k2] = ld4(gbase + (size_t)((chunk + 1) * 32 + c0s + 8 * k2) * (NH * NW));
        }
#pragma unroll
        for (int j = 0; j < 2; j++) {
            const int cl = lg * 2 + j;
            const float* wb = fs + cl * 396 + dyA * 44 + oct * 8;
            float4 w0 = ld4(wb), w1 = ld4(wb + 4), w2 = ld4(wb + 8), w3 = ld4(wb + 12);
            float w[16] = {w0.x, w0.y, w0.z, w0.w, w1.x, w1.y, w1.z, w1.w,
                           w2.x, w2.y, w2.z, w2.w, w3.x, w3.y, w3.z, w3.w};
            const float* fb = S + a_off + (chunk * 32 + cl) * 36 + oct * 8;
            float4 f0 = ld4(fb), f1 = ld4(fb + 4);
            float f[8] = {f0.x, f0.y, f0.z, f0.w, f1.x, f1.y, f1.z, f1.w};
#pragma unroll
            for (int dx = 0; dx < 9; dx++)
#pragma unroll
                for (int i = 0; i < 8; i++)
                    acc[dx][i] = fmaf(f[i], w[i + dx], acc[dx][i]);
        }
        __syncthreads();
    }
    // 4-buffer, 4-phase cross-group reduce (stride-36 rows: conflict-free)
#pragma unroll 1
    for (int p = 0; p < 4; p++) {
        if ((lg >> 2) == p) {
            float* Bf = fs + (lg & 3) * 2916;
#pragma unroll
            for (int dx = 0; dx < 9; dx++) {
                int idx = (dyA * 9 + dx) * 36 + oct * 8;
                if (p == 0) {
                    st4(Bf + idx,     make_float4(acc[dx][0], acc[dx][1], acc[dx][2], acc[dx][3]));
                    st4(Bf + idx + 4, make_float4(acc[dx][4], acc[dx][5], acc[dx][6], acc[dx][7]));
                } else {
                    float4 t0 = ld4(Bf + idx), t1 = ld4(Bf + idx + 4);
                    t0.x += acc[dx][0]; t0.y += acc[dx][1]; t0.z += acc[dx][2]; t0.w += acc[dx][3];
                    t1.x += acc[dx][4]; t1.y += acc[dx][5]; t1.z += acc[dx][6]; t1.w += acc[dx][7];
                    st4(Bf + idx, t0); st4(Bf + idx + 4, t1);
                }
            }
        }
        __syncthreads();
    }
}

// ---------------- mega kernel: one block = one (b,y) row, all 3 iterations ----------------
__global__ __launch_bounds__(576, 2) void mega(const float* __restrict__ flt_in,
                                               const float* __restrict__ feat,
                                               float* __restrict__ out,
                                               float* __restrict__ cst_g,
                                               const float* __restrict__ lw,
                                               const float* __restrict__ mw,
                                               const float* __restrict__ sww,
                                               const float* __restrict__ lsl,
                                               const float* __restrict__ fr) {
    __shared__ float S[L_TOTAL];
    int b, y; map_by(blockIdx.x, b, y);
    const int tid = threadIdx.x;

    // A/C compute mapping
    const int lg  = tid / 36;
    const int r36 = tid - lg * 36;
    const int oct = r36 & 3;
    const int dyA = r36 >> 2;
    // staging mapping (A/C chunks)
    const int qs  = tid & 7;
    const int rs  = tid >> 3;
    const int c0s = rs / 9;
    const int dys = rs - c0s * 9;
    const int rys = y + dys - 4;
    const bool vst = (rys >= 0 && rys < 32);
    // B mapping: lanes read CONSECUTIVE channels -> conflict-free LDS access
    const int octB = tid >> 7;          // 0..3 for active threads
    const int cB   = tid & 127;
    const bool actB = (tid < 512);
    const int qB   = tid & 7;           // B staging
    const int cB0  = tid >> 3;

    // local constants (replaces k_const kernel)
    if (tid < 81) {
        int dyc = tid / 9, dxc = tid - dyc * 9;
        float dist = sqrtf((float)((dyc - 4) * (dyc - 4) + (dxc - 4) * (dxc - 4)));
        float lab = 0.f, mm = 0.f, ss = 0.f;
        for (int d = 0; d < 10; d++) {
            float diff = dist * 2.f - (float)d;
            float bv = (d < 9) ? fmaxf(0.f, 1.f - fabsf(diff))
                               : fminf(fmaxf(1.f + diff, 0.f), 1.f);
            lab += bv * lw[d];
            mm  += bv * mw[d];
            ss  += bv * sww[d];
        }
        S[L_CL + tid]       = lab;
        S[L_CL + 81 + tid]  = 1.f / (1.f + expf(-mm));
        S[L_CL + 162 + tid] = ss;
    } else if (tid == 81) {
        S[L_CL + 243] = expf(lsl[0]);
    } else if (tid == 82) {
        S[L_CL + 244] = fmaxf(fr[0] * fr[0], 1e-10f) * (1.f / 65536.f);
    }
    // stage flt row
    {
        const float* base = flt_in + ((size_t)b * NC * NH + y) * NW;
        for (int i = tid; i < 2048; i += 576) {
            int c = i >> 3, q = i & 7;
            st4(S + L_FLT + c * 36 + q * 4, ld4(base + c * (NH * NW) + q * 4));
        }
    }
    __syncthreads();
    const float step = S[L_CL + 243];
    const float rw   = S[L_CL + 244];

#pragma unroll 1
    for (int it = 0; it < 3; it++) {
        // ---------- pass A: scores = corr(flt), elementwise -> mres/smask, src loss ----------
        corr_pass(S, feat, L_FLT, b, y, tid, lg, oct, dyA, qs, c0s, dys, vst, rys);

        float srcl = 0.f;
        if (tid < 324) {
            const int kk = tid >> 2, o8 = (tid & 3) * 8;
            const int base = kk * 36 + o8;
            const float lab = S[L_CL + kk], m = S[L_CL + 81 + kk], sw = S[L_CL + 162 + kk];
            const float am = 0.5f * (1.f - m), ap = 0.5f * (1.f + m);
#pragma unroll
            for (int h = 0; h < 2; h++) {
                float4 s0 = ld4(S + L_FS + base + h * 4);
                float4 s1 = ld4(S + L_FS + 2916 + base + h * 4);
                float4 s2 = ld4(S + L_FS + 5832 + base + h * 4);
                float4 s3 = ld4(S + L_FS + 8748 + base + h * 4);
                float sv[4] = {s0.x + s1.x + s2.x + s3.x, s0.y + s1.y + s2.y + s3.y,
                               s0.z + s1.z + s2.z + s3.z, s0.w + s1.w + s2.w + s3.w};
                float tr[4], tm[4];
#pragma unroll
                for (int xi = 0; xi < 4; xi++) {
                    float s = sv[xi];
                    float act = am * fabsf(s) + ap * s;
                    float sgn = (s > 0.f ? 1.f : 0.f) - (s < 0.f ? 1.f : 0.f);
                    float msk = am * sgn + ap;
                    float lres = sw * (act - lab);
                    srcl = fmaf(lres, lres, srcl);
                    tr[xi] = msk * sw * lres;
                    tm[xi] = msk;
                }
                st4(S + L_MRES + base + h * 4,  make_float4(tr[0], tr[1], tr[2], tr[3]));
                st4(S + L_SMASK + base + h * 4, make_float4(tm[0], tm[1], tm[2], tm[3]));
            }
        }
#pragma unroll
        for (int off = 32; off > 0; off >>= 1) srcl += __shfl_down(srcl, off, 64);
        if ((tid & 63) == 0) atomicAdd(cst_g + it, srcl);
        __syncthreads();

        // ---------- pass B: fg = corr_T(mres) + rw*flt; alpha_num; reg loss ----------
        {
            const float4 z4 = make_float4(0.f, 0.f, 0.f, 0.f);
            // zero x-halos of B layout [256][44]: quads 0 and 9 of each row
            for (int i = tid; i < 512; i += 576) {
                int c = i >> 1, h = i & 1;
                st4(S + L_FS + c * 44 + (h ? 36 : 0), z4);
            }
            float accb[2][8];
#pragma unroll
            for (int j = 0; j < 2; j++)
#pragma unroll
                for (int i = 0; i < 8; i++) accb[j][i] = 0.f;

            const int dy0 = (y < 4) ? (4 - y) : 0;
            const int dyN = (y > 27) ? (36 - y) : 9;
            float4 R[4];
            if (actB) {
                int ry0 = y + dy0 - 4;
#pragma unroll
                for (int k = 0; k < 4; k++)
                    R[k] = ld4(feat + (((size_t)(b * NC + cB0 + 64 * k)) * NH + ry0) * NW + qB * 4);
            }
#pragma unroll 1
            for (int dy = dy0; dy < dyN; ++dy) {
                __syncthreads();                          // prior compute done reading FS
                if (actB) {
#pragma unroll
                    for (int k = 0; k < 4; k++)
                        st4(S + L_FS + (cB0 + 64 * k) * 44 + 4 + qB * 4, R[k]);
                    if (dy + 1 < dyN) {                   // prefetch next dy into regs
                        int ry = y + dy - 3;
#pragma unroll
                        for (int k = 0; k < 4; k++)
                            R[k] = ld4(feat + (((size_t)(b * NC + cB0 + 64 * k)) * NH + ry) * NW + qB * 4);
                    }
                }
                __syncthreads();
                if (actB) {
                    float rr[9][8];
#pragma unroll
                    for (int dx = 0; dx < 9; dx++) {
                        int mi = (dy * 9 + dx) * 36 + octB * 8;     // wave-uniform addr: broadcast
                        float4 t0 = ld4(S + L_MRES + mi), t1 = ld4(S + L_MRES + mi + 4);
                        rr[dx][0] = t0.x; rr[dx][1] = t0.y; rr[dx][2] = t0.z; rr[dx][3] = t0.w;
                        rr[dx][4] = t1.x; rr[dx][5] = t1.y; rr[dx][6] = t1.z; rr[dx][7] = t1.w;
                    }
#pragma unroll
                    for (int j = 0; j < 2; j++) {
                        const int c = cB + 128 * j;                 // consecutive c across lanes
                        const float* wb = S + L_FS + c * 44 + octB * 8;
                        float4 w0 = ld4(wb), w1 = ld4(wb + 4), w2 = ld4(wb + 8), w3 = ld4(wb + 12);
                        float w[16] = {w0.x, w0.y, w0.z, w0.w, w1.x, w1.y, w1.z, w1.w,
                                       w2.x, w2.y, w2.z, w2.w, w3.x, w3.y, w3.z, w3.w};
#pragma unroll
                        for (int dx = 0; dx < 9; dx++)
#pragma unroll
                            for (int i = 0; i < 8; i++)
                                accb[j][i] = fmaf(rr[dx][i], w[i + dx], accb[j][i]);
                    }
                }
            }
            __syncthreads();   // fs free; fg/anum phase

            float regl = 0.f;
            if (actB) {
                float g[2][8];
#pragma unroll
                for (int j = 0; j < 2; j++) {
                    const int c = cB + 128 * j;
                    const float* fb = S + L_FLT + c * 36 + octB * 8;
                    float4 f0 = ld4(fb), f1 = ld4(fb + 4);
                    float fv[8] = {f0.x, f0.y, f0.z, f0.w, f1.x, f1.y, f1.z, f1.w};
#pragma unroll
                    for (int i = 0; i < 8; i++) {
                        g[j][i] = accb[j][i] + rw * fv[i];
                        regl = fmaf(fv[i], fv[i], regl);
                    }
                    st4(S + L_FG + c * 36 + octB * 8,
                        make_float4(g[j][0], g[j][1], g[j][2], g[j][3]));
                    st4(S + L_FG + c * 36 + octB * 8 + 4,
                        make_float4(g[j][4], g[j][5], g[j][6], g[j][7]));
                }
                float pp[8];
#pragma unroll
                for (int i = 0; i < 8; i++) pp[i] = g[0][i] * g[0][i] + g[1][i] * g[1][i];
                st4(S + L_FS + cB * 36 + octB * 8,     make_float4(pp[0], pp[1], pp[2], pp[3]));
                st4(S + L_FS + cB * 36 + octB * 8 + 4, make_float4(pp[4], pp[5], pp[6], pp[7]));
            }
#pragma unroll
            for (int off = 32; off > 0; off >>= 1) regl += __shfl_down(regl, off, 64);
            if ((tid & 63) == 0) atomicAdd(cst_g + 3 + it, regl);
            __syncthreads();
            if (tid < 32) {
                float s = 0.f;
                for (int c2 = 0; c2 < 128; c2++) s += S[L_FS + c2 * 36 + tid];
                S[L_ANUM + tid] = s;
            }
            __syncthreads();
        }

        // ---------- pass C: sg = corr(fg)*sw*mask; alpha; flt update ----------
        corr_pass(S, feat, L_FG, b, y, tid, lg, oct, dyA, qs, c0s, dys, vst, rys);

        if (tid < 324) {
            const int kk = tid >> 2, o8 = (tid & 3) * 8;
            const int base = kk * 36 + o8;
            const float sw = S[L_CL + 162 + kk];
#pragma unroll
            for (int h = 0; h < 2; h++) {
                float4 s0 = ld4(S + L_FS + base + h * 4);
                float4 s1 = ld4(S + L_FS + 2916 + base + h * 4);
                float4 s2 = ld4(S + L_FS + 5832 + base + h * 4);
                float4 s3 = ld4(S + L_FS + 8748 + base + h * 4);
                float4 mk = ld4(S + L_SMASK + base + h * 4);
                float sg0 = sw * mk.x * (s0.x + s1.x + s2.x + s3.x);
                float sg1 = sw * mk.y * (s0.y + s1.y + s2.y + s3.y);
                float sg2 = sw * mk.z * (s0.z + s1.z + s2.z + s3.z);
                float sg3 = sw * mk.w * (s0.w + s1.w + s2.w + s3.w);
                st4(S + L_MRES + base + h * 4,   // mres dead -> sg^2 scratch
                    make_float4(sg0 * sg0, sg1 * sg1, sg2 * sg2, sg3 * sg3));
            }
        }
        __syncthreads();
        if (tid < 32) {
            float den = 0.f;
            for (int k = 0; k < 81; k++) den += S[L_MRES + k * 36 + tid];
            float num = S[L_ANUM + tid];
            float dd = fmaxf(den + rw * num, 1e-8f);
            S[L_ALPHA + tid] = step * num / dd;
        }
        __syncthreads();
        for (int i = tid; i < 2048; i += 576) {
            int c = i >> 3, q = i & 7;
            float* fp = S + L_FLT + c * 36 + q * 4;
            float4 fl = ld4(fp);
            float4 g = ld4(S + L_FG + c * 36 + q * 4);
            float4 al = ld4(S + L_ALPHA + q * 4);
            fl.x -= al.x * g.x;
            fl.y -= al.y * g.y;
            fl.z -= al.z * g.z;
            fl.w -= al.w * g.w;
            st4(fp, fl);
        }
        __syncthreads();
    }

    // final: write flt row to output
    for (int i = tid; i < 2048; i += 576) {
        int c = i >> 3, q = i & 7;
        st4(out + ((size_t)(b * NC + c) * NH + y) * NW + q * 4,
            ld4(S + L_FLT + c * 36 + q * 4));
    }

    // tail: last-finishing block writes tr/tr_src/tr_reg (replaces k_tail kernel)
    __threadfence();
    if (tid == 0) {
        unsigned int old = atomicAdd((unsigned int*)cst_g + 6, 1u);
        if (old == 511u) {
            for (int i2 = 0; i2 < 3; i2++) {
                float src = 0.5f * atomicAdd(cst_g + i2, 0.f) / 16.f;       // coherent read
                float reg = 0.5f * rw * atomicAdd(cst_g + 3 + i2, 0.f) / 16.f;
                out[4194304 + i2] = src + reg;
                out[4194307 + i2] = src;
                out[4194310 + i2] = reg;
            }
        }
    }
}

extern "C" void kernel_launch(void* const* d_in, const int* in_sizes, int n_in,
                              void* d_out, int out_size, void* d_ws, size_t ws_size,
                              hipStream_t stream) {
    (void)in_sizes; (void)n_in; (void)out_size; (void)ws_size;
    const float* flt_in = (const float*)d_in[0];
    const float* feat   = (const float*)d_in[1];
    const float* lw     = (const float*)d_in[2];
    const float* mw     = (const float*)d_in[3];
    const float* sww    = (const float*)d_in[4];
    const float* lsl    = (const float*)d_in[5];
    const float* fr     = (const float*)d_in[6];
    float* out = (float*)d_out;
    float* cst = (float*)d_ws;

    hipMemsetAsync(cst, 0, 32, stream);   // src[3], reg[3], ctr
    mega<<<512, 576, 0, stream>>>(flt_in, feat, out, cst, lw, mw, sww, lsl, fr);
}

// Round 2
// 536.460 us; speedup vs baseline: 1.1579x; 1.1579x over previous
//
#include <hip/hip_runtime.h>
#include <cstddef>

// ---------------- problem constants ----------------
#define NB 16
#define NC 256
#define NH 32
#define NW 32
#define NK 81

// LDS float offsets (total 37,248 floats = 148,992 B, 1 block/CU)
// Strides chosen so (addr>>2)&7 spreads across all 8 bank-groups:
//   row stride 36 floats -> 9*row = row (mod 8)  [conflict-free vs old 32]
#define L_FLT    0        // [256][36]  flt row
#define L_FG     9216     // [256][36]  filter-grad row
#define L_MRES   18432    // [81][36]   mapped residuals (C reuses as sg^2 scratch)
#define L_SMASK  21348    // [81][36]
#define L_FS     24264    // A/C: [32ch][9dy][44]=12672; red: 4x2916; B: [256][44]=11264; part: [128][36]=4608
#define L_CL     36936    // local consts [245]
#define L_ANUM   37184    // [32]
#define L_ALPHA  37216    // [32]
#define L_TOTAL  37248

__device__ __forceinline__ float4 ld4(const float* p) { return *reinterpret_cast<const float4*>(p); }
__device__ __forceinline__ void st4(float* p, float4 v) { *reinterpret_cast<float4*>(p) = v; }

__device__ __forceinline__ void map_by(int bi, int& b, int& y) {
    int xcd = bi & 7, slot = bi >> 3;
    b = xcd * 2 + (slot >> 5);
    y = slot & 31;
}

// Correlation pass: scores(k,x) = sum_c A[c,x]*featpad[c,y+dy,x+dx-4]
// Results left in 4 red buffers at S[L_FS + p*2916] (stride-36 rows), consumer sums the 4.
__device__ __forceinline__ void corr_pass(float* S, const float* __restrict__ feat,
                                          int a_off, int b, int y, int tid,
                                          int lg, int oct, int dyA,
                                          int qs, int c0s, int dys, bool vst, int rys) {
    float* fs = S + L_FS;
    // prefetch chunk-0 global loads before the zero phase (hide latency)
    const float* gbase = feat + (((size_t)b * NC) * NH + rys) * NW + qs * 4;
    float4 R[4];
    if (vst) {
#pragma unroll
        for (int k2 = 0; k2 < 4; k2++)
            R[k2] = ld4(gbase + (size_t)(c0s + 8 * k2) * (NH * NW));
    }
    const float4 z4 = make_float4(0.f, 0.f, 0.f, 0.f);
    // zero only halo quads (floats 0..3 and 36..39 of each of the 288 [44] rows)
    {
        int row = tid >> 1;
        st4(fs + row * 44 + ((tid & 1) ? 36 : 0), z4);
    }
    // zero full rows of out-of-range dy (only near y edges)
    if (y < 4 || y > 27) {
        for (int dyv = 0; dyv < 9; ++dyv) {
            int ryv = y + dyv - 4;
            if (ryv < 0 || ryv >= 32) {
                for (int i = tid; i < 320; i += 576) {
                    int c = i / 10, q = i - c * 10;
                    st4(fs + c * 396 + dyv * 44 + q * 4, z4);
                }
            }
        }
    }
    __syncthreads();

    float acc[9][8];
#pragma unroll
    for (int dx = 0; dx < 9; dx++)
#pragma unroll
        for (int i = 0; i < 8; i++) acc[dx][i] = 0.f;

#pragma unroll 1
    for (int chunk = 0; chunk < 8; chunk++) {
        if (vst) {
#pragma unroll
            for (int k2 = 0; k2 < 4; k2++)
                st4(fs + (c0s + 8 * k2) * 396 + dys * 44 + 4 + qs * 4, R[k2]);
        }
        __syncthreads();
        if (chunk < 7 && vst) {
#pragma unroll
            for (int k2 = 0; k2 < 4; k2++)
                R[k2] = ld4(gbase + (size_t)((chunk + 1) * 32 + c0s + 8 * k2) * (NH * NW));
        }
#pragma unroll
        for (int j = 0; j < 2; j++) {
            const int cl = lg * 2 + j;
            const float* wb = fs + cl * 396 + dyA * 44 + oct * 8;
            float4 w0 = ld4(wb), w1 = ld4(wb + 4), w2 = ld4(wb + 8), w3 = ld4(wb + 12);
            float w[16] = {w0.x, w0.y, w0.z, w0.w, w1.x, w1.y, w1.z, w1.w,
                           w2.x, w2.y, w2.z, w2.w, w3.x, w3.y, w3.z, w3.w};
            const float* fb = S + a_off + (chunk * 32 + cl) * 36 + oct * 8;
            float4 f0 = ld4(fb), f1 = ld4(fb + 4);
            float f[8] = {f0.x, f0.y, f0.z, f0.w, f1.x, f1.y, f1.z, f1.w};
#pragma unroll
            for (int dx = 0; dx < 9; dx++)
#pragma unroll
                for (int i = 0; i < 8; i++)
                    acc[dx][i] = fmaf(f[i], w[i + dx], acc[dx][i]);
        }
        __syncthreads();
    }
    // 4-buffer, 4-phase cross-group reduce (stride-36 rows: conflict-free)
#pragma unroll 1
    for (int p = 0; p < 4; p++) {
        if ((lg >> 2) == p) {
            float* Bf = fs + (lg & 3) * 2916;
#pragma unroll
            for (int dx = 0; dx < 9; dx++) {
                int idx = (dyA * 9 + dx) * 36 + oct * 8;
                if (p == 0) {
                    st4(Bf + idx,     make_float4(acc[dx][0], acc[dx][1], acc[dx][2], acc[dx][3]));
                    st4(Bf + idx + 4, make_float4(acc[dx][4], acc[dx][5], acc[dx][6], acc[dx][7]));
                } else {
                    float4 t0 = ld4(Bf + idx), t1 = ld4(Bf + idx + 4);
                    t0.x += acc[dx][0]; t0.y += acc[dx][1]; t0.z += acc[dx][2]; t0.w += acc[dx][3];
                    t1.x += acc[dx][4]; t1.y += acc[dx][5]; t1.z += acc[dx][6]; t1.w += acc[dx][7];
                    st4(Bf + idx, t0); st4(Bf + idx + 4, t1);
                }
            }
        }
        __syncthreads();
    }
}

// ---------------- mega kernel: one block = one (b,y) row, all 3 iterations ----------------
__global__ __launch_bounds__(576, 2) void mega(const float* __restrict__ flt_in,
                                               const float* __restrict__ feat,
                                               float* __restrict__ out,
                                               float* __restrict__ cst_g,
                                               const float* __restrict__ lw,
                                               const float* __restrict__ mw,
                                               const float* __restrict__ sww,
                                               const float* __restrict__ lsl,
                                               const float* __restrict__ fr) {
    __shared__ float S[L_TOTAL];
    int b, y; map_by(blockIdx.x, b, y);
    const int tid = threadIdx.x;

    // A/C compute mapping
    const int lg  = tid / 36;
    const int r36 = tid - lg * 36;
    const int oct = r36 & 3;
    const int dyA = r36 >> 2;
    // staging mapping (A/C chunks)
    const int qs  = tid & 7;
    const int rs  = tid >> 3;
    const int c0s = rs / 9;
    const int dys = rs - c0s * 9;
    const int rys = y + dys - 4;
    const bool vst = (rys >= 0 && rys < 32);
    // B mapping: lanes read CONSECUTIVE channels -> conflict-free LDS access
    const int octB = tid >> 7;          // 0..3 for active threads
    const int cB   = tid & 127;
    const bool actB = (tid < 512);
    const int qB   = tid & 7;           // B staging
    const int cB0  = tid >> 3;

    // local constants (k_const folded in; per-block LDS-local, no global handshake)
    if (tid < 81) {
        int dyc = tid / 9, dxc = tid - dyc * 9;
        float dist = sqrtf((float)((dyc - 4) * (dyc - 4) + (dxc - 4) * (dxc - 4)));
        float lab = 0.f, mm = 0.f, ss = 0.f;
        for (int d = 0; d < 10; d++) {
            float diff = dist * 2.f - (float)d;
            float bv = (d < 9) ? fmaxf(0.f, 1.f - fabsf(diff))
                               : fminf(fmaxf(1.f + diff, 0.f), 1.f);
            lab += bv * lw[d];
            mm  += bv * mw[d];
            ss  += bv * sww[d];
        }
        S[L_CL + tid]       = lab;
        S[L_CL + 81 + tid]  = 1.f / (1.f + expf(-mm));
        S[L_CL + 162 + tid] = ss;
    } else if (tid == 81) {
        S[L_CL + 243] = expf(lsl[0]);
    } else if (tid == 82) {
        S[L_CL + 244] = fmaxf(fr[0] * fr[0], 1e-10f) * (1.f / 65536.f);
    }
    // stage flt row
    {
        const float* base = flt_in + ((size_t)b * NC * NH + y) * NW;
        for (int i = tid; i < 2048; i += 576) {
            int c = i >> 3, q = i & 7;
            st4(S + L_FLT + c * 36 + q * 4, ld4(base + c * (NH * NW) + q * 4));
        }
    }
    __syncthreads();
    const float step = S[L_CL + 243];
    const float rw   = S[L_CL + 244];

#pragma unroll 1
    for (int it = 0; it < 3; it++) {
        // ---------- pass A: scores = corr(flt), elementwise -> mres/smask, src loss ----------
        corr_pass(S, feat, L_FLT, b, y, tid, lg, oct, dyA, qs, c0s, dys, vst, rys);

        float srcl = 0.f;
        if (tid < 324) {
            const int kk = tid >> 2, o8 = (tid & 3) * 8;
            const int base = kk * 36 + o8;
            const float lab = S[L_CL + kk], m = S[L_CL + 81 + kk], sw = S[L_CL + 162 + kk];
            const float am = 0.5f * (1.f - m), ap = 0.5f * (1.f + m);
#pragma unroll
            for (int h = 0; h < 2; h++) {
                float4 s0 = ld4(S + L_FS + base + h * 4);
                float4 s1 = ld4(S + L_FS + 2916 + base + h * 4);
                float4 s2 = ld4(S + L_FS + 5832 + base + h * 4);
                float4 s3 = ld4(S + L_FS + 8748 + base + h * 4);
                float sv[4] = {s0.x + s1.x + s2.x + s3.x, s0.y + s1.y + s2.y + s3.y,
                               s0.z + s1.z + s2.z + s3.z, s0.w + s1.w + s2.w + s3.w};
                float tr[4], tm[4];
#pragma unroll
                for (int xi = 0; xi < 4; xi++) {
                    float s = sv[xi];
                    float act = am * fabsf(s) + ap * s;
                    float sgn = (s > 0.f ? 1.f : 0.f) - (s < 0.f ? 1.f : 0.f);
                    float msk = am * sgn + ap;
                    float lres = sw * (act - lab);
                    srcl = fmaf(lres, lres, srcl);
                    tr[xi] = msk * sw * lres;
                    tm[xi] = msk;
                }
                st4(S + L_MRES + base + h * 4,  make_float4(tr[0], tr[1], tr[2], tr[3]));
                st4(S + L_SMASK + base + h * 4, make_float4(tm[0], tm[1], tm[2], tm[3]));
            }
        }
#pragma unroll
        for (int off = 32; off > 0; off >>= 1) srcl += __shfl_down(srcl, off, 64);
        if ((tid & 63) == 0) atomicAdd(cst_g + it, srcl);
        __syncthreads();

        // ---------- pass B: fg = corr_T(mres) + rw*flt; alpha_num; reg loss ----------
        {
            const float4 z4 = make_float4(0.f, 0.f, 0.f, 0.f);
            // zero x-halos of B layout [256][44]: quads 0 and 9 of each row
            for (int i = tid; i < 512; i += 576) {
                int c = i >> 1, h = i & 1;
                st4(S + L_FS + c * 44 + (h ? 36 : 0), z4);
            }
            float accb[2][8];
#pragma unroll
            for (int j = 0; j < 2; j++)
#pragma unroll
                for (int i = 0; i < 8; i++) accb[j][i] = 0.f;

            const int dy0 = (y < 4) ? (4 - y) : 0;
            const int dyN = (y > 27) ? (36 - y) : 9;
            float4 R[4];
            if (actB) {
                int ry0 = y + dy0 - 4;
#pragma unroll
                for (int k = 0; k < 4; k++)
                    R[k] = ld4(feat + (((size_t)(b * NC + cB0 + 64 * k)) * NH + ry0) * NW + qB * 4);
            }
#pragma unroll 1
            for (int dy = dy0; dy < dyN; ++dy) {
                __syncthreads();                          // prior compute done reading FS
                if (actB) {
#pragma unroll
                    for (int k = 0; k < 4; k++)
                        st4(S + L_FS + (cB0 + 64 * k) * 44 + 4 + qB * 4, R[k]);
                    if (dy + 1 < dyN) {                   // prefetch next dy into regs
                        int ry = y + dy - 3;
#pragma unroll
                        for (int k = 0; k < 4; k++)
                            R[k] = ld4(feat + (((size_t)(b * NC + cB0 + 64 * k)) * NH + ry) * NW + qB * 4);
                    }
                }
                __syncthreads();
                if (actB) {
                    float rr[9][8];
#pragma unroll
                    for (int dx = 0; dx < 9; dx++) {
                        int mi = (dy * 9 + dx) * 36 + octB * 8;     // wave-uniform addr: broadcast
                        float4 t0 = ld4(S + L_MRES + mi), t1 = ld4(S + L_MRES + mi + 4);
                        rr[dx][0] = t0.x; rr[dx][1] = t0.y; rr[dx][2] = t0.z; rr[dx][3] = t0.w;
                        rr[dx][4] = t1.x; rr[dx][5] = t1.y; rr[dx][6] = t1.z; rr[dx][7] = t1.w;
                    }
#pragma unroll
                    for (int j = 0; j < 2; j++) {
                        const int c = cB + 128 * j;                 // consecutive c across lanes
                        const float* wb = S + L_FS + c * 44 + octB * 8;
                        float4 w0 = ld4(wb), w1 = ld4(wb + 4), w2 = ld4(wb + 8), w3 = ld4(wb + 12);
                        float w[16] = {w0.x, w0.y, w0.z, w0.w, w1.x, w1.y, w1.z, w1.w,
                                       w2.x, w2.y, w2.z, w2.w, w3.x, w3.y, w3.z, w3.w};
#pragma unroll
                        for (int dx = 0; dx < 9; dx++)
#pragma unroll
                            for (int i = 0; i < 8; i++)
                                accb[j][i] = fmaf(rr[dx][i], w[i + dx], accb[j][i]);
                    }
                }
            }
            __syncthreads();   // fs free; fg/anum phase

            float regl = 0.f;
            if (actB) {
                float g[2][8];
#pragma unroll
                for (int j = 0; j < 2; j++) {
                    const int c = cB + 128 * j;
                    const float* fb = S + L_FLT + c * 36 + octB * 8;
                    float4 f0 = ld4(fb), f1 = ld4(fb + 4);
                    float fv[8] = {f0.x, f0.y, f0.z, f0.w, f1.x, f1.y, f1.z, f1.w};
#pragma unroll
                    for (int i = 0; i < 8; i++) {
                        g[j][i] = accb[j][i] + rw * fv[i];
                        regl = fmaf(fv[i], fv[i], regl);
                    }
                    st4(S + L_FG + c * 36 + octB * 8,
                        make_float4(g[j][0], g[j][1], g[j][2], g[j][3]));
                    st4(S + L_FG + c * 36 + octB * 8 + 4,
                        make_float4(g[j][4], g[j][5], g[j][6], g[j][7]));
                }
                float pp[8];
#pragma unroll
                for (int i = 0; i < 8; i++) pp[i] = g[0][i] * g[0][i] + g[1][i] * g[1][i];
                st4(S + L_FS + cB * 36 + octB * 8,     make_float4(pp[0], pp[1], pp[2], pp[3]));
                st4(S + L_FS + cB * 36 + octB * 8 + 4, make_float4(pp[4], pp[5], pp[6], pp[7]));
            }
#pragma unroll
            for (int off = 32; off > 0; off >>= 1) regl += __shfl_down(regl, off, 64);
            if ((tid & 63) == 0) atomicAdd(cst_g + 3 + it, regl);
            __syncthreads();
            if (tid < 32) {
                float s = 0.f;
                for (int c2 = 0; c2 < 128; c2++) s += S[L_FS + c2 * 36 + tid];
                S[L_ANUM + tid] = s;
            }
            __syncthreads();
        }

        // ---------- pass C: sg = corr(fg)*sw*mask; alpha; flt update ----------
        corr_pass(S, feat, L_FG, b, y, tid, lg, oct, dyA, qs, c0s, dys, vst, rys);

        if (tid < 324) {
            const int kk = tid >> 2, o8 = (tid & 3) * 8;
            const int base = kk * 36 + o8;
            const float sw = S[L_CL + 162 + kk];
#pragma unroll
            for (int h = 0; h < 2; h++) {
                float4 s0 = ld4(S + L_FS + base + h * 4);
                float4 s1 = ld4(S + L_FS + 2916 + base + h * 4);
                float4 s2 = ld4(S + L_FS + 5832 + base + h * 4);
                float4 s3 = ld4(S + L_FS + 8748 + base + h * 4);
                float4 mk = ld4(S + L_SMASK + base + h * 4);
                float sg0 = sw * mk.x * (s0.x + s1.x + s2.x + s3.x);
                float sg1 = sw * mk.y * (s0.y + s1.y + s2.y + s3.y);
                float sg2 = sw * mk.z * (s0.z + s1.z + s2.z + s3.z);
                float sg3 = sw * mk.w * (s0.w + s1.w + s2.w + s3.w);
                st4(S + L_MRES + base + h * 4,   // mres dead -> sg^2 scratch
                    make_float4(sg0 * sg0, sg1 * sg1, sg2 * sg2, sg3 * sg3));
            }
        }
        __syncthreads();
        if (tid < 32) {
            float den = 0.f;
            for (int k = 0; k < 81; k++) den += S[L_MRES + k * 36 + tid];
            float num = S[L_ANUM + tid];
            float dd = fmaxf(den + rw * num, 1e-8f);
            S[L_ALPHA + tid] = step * num / dd;
        }
        __syncthreads();
        for (int i = tid; i < 2048; i += 576) {
            int c = i >> 3, q = i & 7;
            float* fp = S + L_FLT + c * 36 + q * 4;
            float4 fl = ld4(fp);
            float4 g = ld4(S + L_FG + c * 36 + q * 4);
            float4 al = ld4(S + L_ALPHA + q * 4);
            fl.x -= al.x * g.x;
            fl.y -= al.y * g.y;
            fl.z -= al.z * g.z;
            fl.w -= al.w * g.w;
            st4(fp, fl);
        }
        __syncthreads();
    }

    // final: write flt row to output
    for (int i = tid; i < 2048; i += 576) {
        int c = i >> 3, q = i & 7;
        st4(out + ((size_t)(b * NC + c) * NH + y) * NW + q * 4,
            ld4(S + L_FLT + c * 36 + q * 4));
    }
}

// ---------------- tail: write tr, tr_src, tr_reg (separate dispatch, no fences in mega) ----------------
__global__ void k_tail(const float* __restrict__ cst, const float* __restrict__ fr,
                       float* __restrict__ out) {
    int i = threadIdx.x;
    if (i < 3) {
        float rw = fmaxf(fr[0] * fr[0], 1e-10f) * (1.f / 65536.f);
        float src = 0.5f * cst[i] / 16.f;
        float reg = 0.5f * rw * cst[3 + i] / 16.f;
        out[4194304 + i] = src + reg;
        out[4194307 + i] = src;
        out[4194310 + i] = reg;
    }
}

extern "C" void kernel_launch(void* const* d_in, const int* in_sizes, int n_in,
                              void* d_out, int out_size, void* d_ws, size_t ws_size,
                              hipStream_t stream) {
    (void)in_sizes; (void)n_in; (void)out_size; (void)ws_size;
    const float* flt_in = (const float*)d_in[0];
    const float* feat   = (const float*)d_in[1];
    const float* lw     = (const float*)d_in[2];
    const float* mw     = (const float*)d_in[3];
    const float* sww    = (const float*)d_in[4];
    const float* lsl    = (const float*)d_in[5];
    const float* fr     = (const float*)d_in[6];
    float* out = (float*)d_out;
    float* cst = (float*)d_ws;

    hipMemsetAsync(cst, 0, 32, stream);   // src[3], reg[3]
    mega<<<512, 576, 0, stream>>>(flt_in, feat, out, cst, lw, mw, sww, lsl, fr);
    k_tail<<<1, 64, 0, stream>>>(cst, fr, out);
}